// Round 10
// baseline (471.794 us; speedup 1.0000x reference)
//
#include <hip/hip_runtime.h>
#include <hip/hip_bf16.h>

// ---------------------------------------------------------------------------
// SemanticComposite: attention-like mix + 3-gate combine.
// R10 = R8 resubmitted (rounds 8 and 9 both hit GPU-acquisition timeouts).
// R8: pl halved (split P write/consume per ks2): LDS 81920 -> 73728
//     so TWO blocks/CU can co-reside (R7's 81920*2 = exact pool = refused).
//     __launch_bounds__(512,4) pins VGPR<=128 (4 waves/SIMD).
// LESSONS: (R5/R6) 1024-thr blocks pin VGPR to 64+64 -> spills this kernel.
//          (R7) 2x81920 = exact 160 KiB does NOT co-schedule.
// ---------------------------------------------------------------------------

typedef unsigned short u16;
typedef unsigned int   u32;
typedef u16   u16x8 __attribute__((ext_vector_type(8)));
typedef u16   u16x4 __attribute__((ext_vector_type(4)));
typedef short s16x8 __attribute__((ext_vector_type(8)));
typedef float f32x4 __attribute__((ext_vector_type(4)));

#define MFMA16(a,b,c) __builtin_amdgcn_mfma_f32_16x16x32_bf16( \
    __builtin_bit_cast(s16x8,(a)), __builtin_bit_cast(s16x8,(b)), (c), 0, 0, 0)

static __device__ __forceinline__ u16 f2bf(float f) {
  __hip_bfloat16 h = __float2bfloat16(f);
  return *reinterpret_cast<u16*>(&h);
}
static __device__ __forceinline__ float bf2f(u16 v) {
  u32 t = ((u32)v) << 16;
  return __builtin_bit_cast(float, t);
}

#define NB   8
#define NS   2048
#define NF   256
#define NR   (NB*NS)          // 16384 rows

// vt swizzle: spreads both pr-clusters and a-clusters across banks.
#define VSWZ(f) ((((f) & 7) << 4) ^ ((((f) >> 3) & 3) << 5))

// ---------------- prep: qb = bf16(x*wc), xb = bf16(x), bvec = x.wb ---------
__global__ __launch_bounds__(256) void k_prep(const float* __restrict__ x,
                                              const float* __restrict__ attw,
                                              u16* __restrict__ qb,
                                              u16* __restrict__ xb,
                                              float* __restrict__ bvec) {
  const int lane = threadIdx.x & 63, w = threadIdx.x >> 6;
  const int row = blockIdx.x * 4 + w;                 // 0..16383
  const float4 xv = *reinterpret_cast<const float4*>(x + (size_t)row * NF + lane * 4);
  const float4 wc = *reinterpret_cast<const float4*>(attw + 2 * NF + lane * 4);
  const float4 wb = *reinterpret_cast<const float4*>(attw + NF + lane * 4);
  u16x4 q, xq;
  q[0] = f2bf(xv.x * wc.x); q[1] = f2bf(xv.y * wc.y);
  q[2] = f2bf(xv.z * wc.z); q[3] = f2bf(xv.w * wc.w);
  xq[0] = f2bf(xv.x); xq[1] = f2bf(xv.y); xq[2] = f2bf(xv.z); xq[3] = f2bf(xv.w);
  *reinterpret_cast<u16x4*>(qb + (size_t)row * NF + lane * 4) = q;
  *reinterpret_cast<u16x4*>(xb + (size_t)row * NF + lane * 4) = xq;
  float s = xv.x * wb.x + xv.y * wb.y + xv.z * wb.z + xv.w * wb.w;
  #pragma unroll
  for (int m = 1; m < 64; m <<= 1) s += __shfl_xor(s, m, 64);
  if (lane == 0) bvec[row] = s;
}

// ---------------- weight repack to B-fragment-linear bf16 ------------------
__global__ __launch_bounds__(64) void k_wrep(const float* __restrict__ zw,
                                             const float* __restrict__ rw,
                                             const float* __restrict__ fw,
                                             u16* __restrict__ wfrag) {
  const int lane = threadIdx.x & 63;
  const int idx = blockIdx.x;                   // 0..767
  const int w = idx >> 8, rem = idx & 255, ks = rem >> 4, nt = rem & 15;
  const float* W = (w == 0) ? zw : ((w == 1) ? rw : fw);
  const int n = lane & 15, g = lane >> 4;
  const float* src = W + (size_t)(nt * 16 + n) * 512 + ks * 32 + g * 8;
  u16x8 o;
  #pragma unroll
  for (int i = 0; i < 8; ++i) o[i] = f2bf(src[i]);
  *reinterpret_cast<u16x8*>(wfrag + ((size_t)(w * 256 + ks * 16 + nt) * 64 + lane) * 8) = o;
}

// ---------------- flash attention (R8) -------------------------------------
// grid 512 = (b = blk&7 [XCD], rest: itile = rest>>1, jh = rest&1).
// 512 thr = 8 waves: wr = w&3 -> 16-row quarter; wg = w>>2 -> j-sub-half
// (512 j, 8 jtt of 64). LDS 73728 B: vt[2 wg][256 f][64 j] bf16 swz (65536)
// + pl[8 wave][16 row][32 j] bf16 swz (8192), P split per ks2 half.
// Merge aliases: Of->vt, ML->pl. Output: normalized bf16 partial + (M,L).
__global__ __launch_bounds__(512, 4) void k_attn(const u16* __restrict__ qb,
                                                 const u16* __restrict__ xb,
                                                 const float* __restrict__ bvec,
                                                 u16* __restrict__ po0,
                                                 u16* __restrict__ po1,
                                                 float* __restrict__ mlp) {
  extern __shared__ u16 lds[];
  const int tid = threadIdx.x;
  const int w = tid >> 6, lane = tid & 63;
  const int wr = w & 3, wg = w >> 2;
  const int n = lane & 15, g = lane >> 4;
  const int b = blockIdx.x & 7, rest = blockIdx.x >> 3;
  const int itile = rest >> 1, jh = rest & 1;
  const int i0 = itile * 64;
  const size_t xbase = (size_t)b * (NS * NF);

  char* vt = reinterpret_cast<char*>(lds) + wg * 32768;
  char* pl = reinterpret_cast<char*>(lds) + 65536 + w * 1024;

  // Q fragments for this wave's 16 rows: 8 ks chunks
  u16x8 qf[8];
  {
    const u16* qrow = qb + xbase + (size_t)(i0 + 16 * wr + n) * NF + 8 * g;
    #pragma unroll
    for (int ks = 0; ks < 8; ++ks) qf[ks] = *reinterpret_cast<const u16x8*>(qrow + 32 * ks);
  }

  f32x4 O[16];
  #pragma unroll
  for (int nf = 0; nf < 16; ++nf) O[nf] = 0.f;
  float mrow[4], lrow[4];
  #pragma unroll
  for (int r = 0; r < 4; ++r) { mrow[r] = -__builtin_inff(); lrow[r] = 0.f; }

  for (int jtt = 0; jtt < 8; ++jtt) {
    const int j0 = jh * 1024 + wg * 512 + jtt * 64;
    // ---- stage V^T tile [256 f][64 j] (group = 256 threads, pair-packed) --
    {
      const int tg = tid & 255;
      const int pr = tg >> 3, a = tg & 7;            // j-pair 0..31, f-chunk
      #pragma unroll
      for (int it = 0; it < 4; ++it) {
        const int c = 8 * (a + 8 * it);
        const u16* r0 = xb + xbase + (size_t)(j0 + 2 * pr) * NF + c;
        u16x8 v0 = *reinterpret_cast<const u16x8*>(r0);
        u16x8 v1 = *reinterpret_cast<const u16x8*>(r0 + NF);
        #pragma unroll
        for (int i = 0; i < 8; ++i) {
          const int f = c + i;
          const u32 pk = (u32)v0[i] | ((u32)v1[i] << 16);
          const int byte = (f * 128 + 4 * pr) ^ VSWZ(f);
          *reinterpret_cast<u32*>(vt + byte) = pk;
        }
      }
    }
    __syncthreads();
    // ---- QK^T: 4 nf x 8 ks, K B-frags direct from global (L1/L2) ----------
    f32x4 sc[4];
    #pragma unroll
    for (int nf = 0; nf < 4; ++nf) {
      f32x4 acc = 0.f;
      const u16* krow = xb + xbase + (size_t)(j0 + 16 * nf + n) * NF + 8 * g;
      __builtin_amdgcn_s_setprio(1);
      #pragma unroll
      for (int ks = 0; ks < 8; ++ks) {
        u16x8 kf = *reinterpret_cast<const u16x8*>(krow + 32 * ks);
        acc = MFMA16(qf[ks], kf, acc);
      }
      __builtin_amdgcn_s_setprio(0);
      const float bv = bvec[b * NS + j0 + 16 * nf + n];
      #pragma unroll
      for (int r = 0; r < 4; ++r) sc[nf][r] = acc[r] + bv;
    }
    // ---- online softmax (rows = 4g+r, cols = n across 4 nf) ---------------
    float pmax[4];
    #pragma unroll
    for (int r = 0; r < 4; ++r) {
      float v = fmaxf(fmaxf(sc[0][r], sc[1][r]), fmaxf(sc[2][r], sc[3][r]));
      #pragma unroll
      for (int m = 1; m < 16; m <<= 1) v = fmaxf(v, __shfl_xor(v, m, 64));
      pmax[r] = v;
    }
    int needi = 0;
    #pragma unroll
    for (int r = 0; r < 4; ++r) needi |= (pmax[r] > mrow[r] + 8.0f) ? 1 : 0;
    if (__any(needi)) {               // T13 defer-max
      #pragma unroll
      for (int r = 0; r < 4; ++r) {
        const float mn = fmaxf(mrow[r], pmax[r]);
        const float scl = __expf(mrow[r] - mn);
        mrow[r] = mn; lrow[r] *= scl;
        #pragma unroll
        for (int nf = 0; nf < 16; ++nf) O[nf][r] *= scl;
      }
    }
    float p[4][4];
    #pragma unroll
    for (int nf = 0; nf < 4; ++nf)
      #pragma unroll
      for (int r = 0; r < 4; ++r) p[nf][r] = __expf(sc[nf][r] - mrow[r]);
    #pragma unroll
    for (int r = 0; r < 4; ++r) {
      float s = p[0][r] + p[1][r] + p[2][r] + p[3][r];
      #pragma unroll
      for (int m = 1; m < 16; m <<= 1) s += __shfl_xor(s, m, 64);
      lrow[r] += s;
    }
    // ---- P -> pl (half-tile [16 row][32 j], swizzled) -> pa -> PV ---------
    // Write nf pair {2ks2, 2ks2+1}, consume, overwrite for ks2=1.
    #pragma unroll
    for (int ks2 = 0; ks2 < 2; ++ks2) {
      #pragma unroll
      for (int nf2 = 0; nf2 < 2; ++nf2) {
        const int nf = 2 * ks2 + nf2;
        #pragma unroll
        for (int r = 0; r < 4; ++r) {
          const int row = 4 * g + r, colp = 16 * nf2 + n;   // j' = j - 32*ks2
          const int byte = (row * 64 + 2 * colp) ^ ((row & 3) << 4);
          *reinterpret_cast<u16*>(pl + byte) = f2bf(p[nf][r]);
        }
      }
      const int pbyte = (n * 64 + 16 * g) ^ ((n & 3) << 4);
      u16x8 pa = *reinterpret_cast<const u16x8*>(pl + pbyte);
      __builtin_amdgcn_s_setprio(1);
      #pragma unroll
      for (int nf16 = 0; nf16 < 16; ++nf16) {
        const int f = 16 * nf16 + n;
        const int vbyte = (f * 128 + 16 * g + 64 * ks2) ^ VSWZ(f);
        u16x8 vf = *reinterpret_cast<const u16x8*>(vt + vbyte);
        O[nf16] = MFMA16(pa, vf, O[nf16]);
      }
      __builtin_amdgcn_s_setprio(0);
    }
    __syncthreads();
  }

  // ---- 2-way merge across wg; write normalized bf16 partial + (M,L) ------
  float* MLm = reinterpret_cast<float*>(reinterpret_cast<char*>(lds) + 65536); // aliases pl (dead)
  if (n == 0) {
    #pragma unroll
    for (int r = 0; r < 4; ++r) {
      const int row = 16 * wr + 4 * g + r;
      MLm[(wg * 64 + row) * 2]     = mrow[r];
      MLm[(wg * 64 + row) * 2 + 1] = lrow[r];
    }
  }
  __syncthreads();                                   // B1
  float fac[4], rL[4];
  #pragma unroll
  for (int r = 0; r < 4; ++r) {
    const int row = 16 * wr + 4 * g + r;
    const float m0 = MLm[row * 2],        l0 = MLm[row * 2 + 1];
    const float m1 = MLm[(64 + row) * 2], l1 = MLm[(64 + row) * 2 + 1];
    const float M = fmaxf(m0, m1);
    const float L = l0 * __expf(m0 - M) + l1 * __expf(m1 - M);
    fac[r] = __expf(mrow[r] - M);
    rL[r]  = 1.0f / L;
    if (wg == 0 && n == 0) {
      const size_t mb = ((size_t)((b * 32 + itile) * 2 + jh)) * 128 + row * 2;
      mlp[mb]     = M;
      mlp[mb + 1] = L;
    }
  }
  char* Of = reinterpret_cast<char*>(lds);           // aliases vt (dead)
  #define OBYTE(row, col) (((row) * 1024 + 4 * (col)) ^ (((row) & 12) << 3))
  if (wg == 1) {
    #pragma unroll
    for (int nf16 = 0; nf16 < 16; ++nf16)
      #pragma unroll
      for (int r = 0; r < 4; ++r) {
        const int row = 16 * wr + 4 * g + r, col = 16 * nf16 + n;
        *reinterpret_cast<float*>(Of + OBYTE(row, col)) = O[nf16][r] * fac[r];
      }
  }
  __syncthreads();                                   // B2
  if (wg == 0) {
    u16* po = jh ? po1 : po0;
    const size_t pbase = (size_t)(b * 32 + itile) * 64 * NF;
    #pragma unroll
    for (int nf16 = 0; nf16 < 16; ++nf16)
      #pragma unroll
      for (int r = 0; r < 4; ++r) {
        const int row = 16 * wr + 4 * g + r, col = 16 * nf16 + n;
        const float v = (O[nf16][r] * fac[r] +
            *reinterpret_cast<const float*>(Of + OBYTE(row, col))) * rL[r];
        po[pbase + (size_t)row * NF + col] = f2bf(v);
      }
  }
}

// ---------------- merge the two j-half partials (in place into po0) --------
__global__ __launch_bounds__(256) void k_amerge(const u16* __restrict__ po0,
                                                const u16* __restrict__ po1,
                                                const float* __restrict__ mlp,
                                                u16* __restrict__ attnb) {
  const int q = blockIdx.x * 256 + threadIdx.x;      // 0..1048575
  const int row = q >> 6;                            // 0..16383
  const int c4 = (q & 63) << 2;
  const int tile = row >> 6, rl = row & 63;
  const size_t m0b = ((size_t)(tile * 2 + 0)) * 128 + rl * 2;
  const size_t m1b = ((size_t)(tile * 2 + 1)) * 128 + rl * 2;
  const float M0 = mlp[m0b], L0 = mlp[m0b + 1];
  const float M1 = mlp[m1b], L1 = mlp[m1b + 1];
  const float M = fmaxf(M0, M1);
  float a0 = L0 * __expf(M0 - M), a1 = L1 * __expf(M1 - M);
  const float rT = 1.0f / (a0 + a1);
  a0 *= rT; a1 *= rT;
  const size_t off = (size_t)row * NF + c4;
  const u16x4 v0 = *reinterpret_cast<const u16x4*>(po0 + off);
  const u16x4 v1 = *reinterpret_cast<const u16x4*>(po1 + off);
  u16x4 o;
  #pragma unroll
  for (int i = 0; i < 4; ++i) o[i] = f2bf(bf2f(v0[i]) * a0 + bf2f(v1[i]) * a1);
  *reinterpret_cast<u16x4*>(attnb + off) = o;
}

// ---------------- fused gate GEMMs + epilogue ------------------------------
// grid 1024 x 256 thr: block = 16 rows; wave w -> col quarter (nt = 4w+nt2).
__global__ __launch_bounds__(256, 4) void k_gate(const u16* __restrict__ xb,
                                                 const u16* __restrict__ attnb,
                                                 const float* __restrict__ x,
                                                 const float* __restrict__ zb,
                                                 const float* __restrict__ rb,
                                                 const float* __restrict__ fb,
                                                 const u16* __restrict__ wfrag,
                                                 float* __restrict__ out) {
  const int tid = threadIdx.x, w = tid >> 6, lane = tid & 63;
  const int m0 = blockIdx.x * 16;
  const int n = lane & 15, g = lane >> 4;

  u16x8 af[16];
  {
    const int row = m0 + n;
    const u16* xr = xb + (size_t)row * NF + 8 * g;
    #pragma unroll
    for (int ks = 0; ks < 8; ++ks) af[ks] = *reinterpret_cast<const u16x8*>(xr + 32 * ks);
    const u16* ar = attnb + (size_t)row * NF + 8 * g;
    #pragma unroll
    for (int ks = 0; ks < 8; ++ks) af[8 + ks] = *reinterpret_cast<const u16x8*>(ar + 32 * ks);
  }
  #pragma unroll
  for (int nt2 = 0; nt2 < 4; ++nt2) {
    const int nt = 4 * w + nt2;
    const int col = 16 * nt + n;
    f32x4 za = zb[col], ra = rb[col], fa = fb[col];
    #pragma unroll
    for (int ks = 0; ks < 16; ++ks) {
      const size_t base = ((size_t)(ks * 16 + nt) * 64 + lane) * 8;
      u16x8 bz  = *reinterpret_cast<const u16x8*>(wfrag + base);
      u16x8 br  = *reinterpret_cast<const u16x8*>(wfrag + (size_t)256 * 64 * 8 + base);
      u16x8 bff = *reinterpret_cast<const u16x8*>(wfrag + (size_t)512 * 64 * 8 + base);
      za = MFMA16(af[ks], bz, za);
      ra = MFMA16(af[ks], br, ra);
      fa = MFMA16(af[ks], bff, fa);
    }
    #pragma unroll
    for (int r = 0; r < 4; ++r) {
      const int row = m0 + 4 * g + r;
      const float xv = x[(size_t)row * NF + col];
      const float zv = 2.f / (1.f + __expf(-2.f * za[r])) - 1.f;  // tanh
      const float rv = 1.f / (1.f + __expf(-ra[r]));
      const float fv = 1.f / (1.f + __expf(-fa[r]));
      out[(size_t)row * NF + col] = rv * xv + fv * zv;
    }
  }
}

// ---------------------------------------------------------------------------
extern "C" void kernel_launch(void* const* d_in, const int* in_sizes, int n_in,
                              void* d_out, int out_size, void* d_ws, size_t ws_size,
                              hipStream_t stream) {
  const float* x    = (const float*)d_in[0];
  const float* attw = (const float*)d_in[1];
  const float* zw   = (const float*)d_in[2];
  const float* zb   = (const float*)d_in[3];
  const float* rw   = (const float*)d_in[4];
  const float* rb   = (const float*)d_in[5];
  const float* fw   = (const float*)d_in[6];
  const float* fb   = (const float*)d_in[7];
  float* out = (float*)d_out;

  char* ws = (char*)d_ws;
  u16*   qb    = (u16*)(ws);                       //  8 MB
  u16*   xbb   = (u16*)(ws + 8388608);             //  8 MB
  u16*   po0   = (u16*)(ws + 16777216);            //  8 MB (partial 0 / final attnb)
  float* bvec  = (float*)(ws + 25165824);          // 64 KB
  u16*   wfrag = (u16*)(ws + 25231360);            // 768 KB -> ends 26017792
  u16*   po1   = (u16*)(ws + 26214400);            //  8 MB (partial 1)
  float* mlp   = (float*)(ws + 34603008);          // 256 KB -> ends ~33.3 MB

  (void)hipFuncSetAttribute((const void*)k_attn,
      hipFuncAttributeMaxDynamicSharedMemorySize, 73728);

  k_prep<<<NR / 4, 256, 0, stream>>>(x, attw, qb, xbb, bvec);
  k_wrep<<<768, 64, 0, stream>>>(zw, rw, fw, wfrag);
  k_attn<<<512, 512, 73728, stream>>>(qb, xbb, bvec, po0, po1, mlp);
  k_amerge<<<4096, 256, 0, stream>>>(po0, po1, mlp, po0);
  k_gate<<<1024, 256, 0, stream>>>(xbb, po0, x, zb, rb, fb, wfrag, out);
}

// Round 11
// 378.157 us; speedup vs baseline: 1.2476x; 1.2476x over previous
//
#include <hip/hip_runtime.h>
#include <hip/hip_bf16.h>

// ---------------------------------------------------------------------------
// SemanticComposite: attention-like mix + 3-gate combine.
// R11: barrier-free flash attention. Each wave owns a PRIVATE 32-j V^T tile
//  (no __syncthreads in the main loop -> waves overlap each other's latency),
//  softmax fast-path with NO per-iter shfl reduces (any-check + deferred
//  row-sum partials), in-block 2-way merge -> k_amerge dropped.
// LESSONS: (R5/R6/R10) launch_bounds waves-hint >=4 or 1024-thr blocks cap
//  unified VGPR at 128 -> spills this wave state. Only (512,1) is safe.
//  (R7) 2x81920 LDS = exact pool does not co-schedule. Occupancy is stuck at
//  1 block/CU for this state; attack latency overlap instead.
// ---------------------------------------------------------------------------

typedef unsigned short u16;
typedef unsigned int   u32;
typedef u16   u16x8 __attribute__((ext_vector_type(8)));
typedef u16   u16x4 __attribute__((ext_vector_type(4)));
typedef short s16x8 __attribute__((ext_vector_type(8)));
typedef float f32x4 __attribute__((ext_vector_type(4)));

#define MFMA16(a,b,c) __builtin_amdgcn_mfma_f32_16x16x32_bf16( \
    __builtin_bit_cast(s16x8,(a)), __builtin_bit_cast(s16x8,(b)), (c), 0, 0, 0)

static __device__ __forceinline__ u16 f2bf(float f) {
  __hip_bfloat16 h = __float2bfloat16(f);
  return *reinterpret_cast<u16*>(&h);
}

#define NB   8
#define NS   2048
#define NF   256
#define NR   (NB*NS)          // 16384 rows

// ---------------- prep: qb = bf16(x*wc), xb = bf16(x), bvec = x.wb ---------
__global__ __launch_bounds__(256) void k_prep(const float* __restrict__ x,
                                              const float* __restrict__ attw,
                                              u16* __restrict__ qb,
                                              u16* __restrict__ xb,
                                              float* __restrict__ bvec) {
  const int lane = threadIdx.x & 63, w = threadIdx.x >> 6;
  const int row = blockIdx.x * 4 + w;                 // 0..16383
  const float4 xv = *reinterpret_cast<const float4*>(x + (size_t)row * NF + lane * 4);
  const float4 wc = *reinterpret_cast<const float4*>(attw + 2 * NF + lane * 4);
  const float4 wb = *reinterpret_cast<const float4*>(attw + NF + lane * 4);
  u16x4 q, xq;
  q[0] = f2bf(xv.x * wc.x); q[1] = f2bf(xv.y * wc.y);
  q[2] = f2bf(xv.z * wc.z); q[3] = f2bf(xv.w * wc.w);
  xq[0] = f2bf(xv.x); xq[1] = f2bf(xv.y); xq[2] = f2bf(xv.z); xq[3] = f2bf(xv.w);
  *reinterpret_cast<u16x4*>(qb + (size_t)row * NF + lane * 4) = q;
  *reinterpret_cast<u16x4*>(xb + (size_t)row * NF + lane * 4) = xq;
  float s = xv.x * wb.x + xv.y * wb.y + xv.z * wb.z + xv.w * wb.w;
  #pragma unroll
  for (int m = 1; m < 64; m <<= 1) s += __shfl_xor(s, m, 64);
  if (lane == 0) bvec[row] = s;
}

// ---------------- weight repack to B-fragment-linear bf16 ------------------
__global__ __launch_bounds__(64) void k_wrep(const float* __restrict__ zw,
                                             const float* __restrict__ rw,
                                             const float* __restrict__ fw,
                                             u16* __restrict__ wfrag) {
  const int lane = threadIdx.x & 63;
  const int idx = blockIdx.x;                   // 0..767
  const int w = idx >> 8, rem = idx & 255, ks = rem >> 4, nt = rem & 15;
  const float* W = (w == 0) ? zw : ((w == 1) ? rw : fw);
  const int n = lane & 15, g = lane >> 4;
  const float* src = W + (size_t)(nt * 16 + n) * 512 + ks * 32 + g * 8;
  u16x8 o;
  #pragma unroll
  for (int i = 0; i < 8; ++i) o[i] = f2bf(src[i]);
  *reinterpret_cast<u16x8*>(wfrag + ((size_t)(w * 256 + ks * 16 + nt) * 64 + lane) * 8) = o;
}

// ---------------- flash attention (R11, barrier-free) ----------------------
// grid 256 = (b = blk&7 [XCD], itile = blk>>3 -> 64 rows). 512 thr = 8 waves:
// wr = w&3 -> 16-row quarter; wg = w>>2 -> j parity. Each wave privately
// stages [256 f][32 j] V^T (16 KB) and loops 32 j-tiles with NO barriers.
// LDS 139264 B: vt[8][16384] + pl[8][1024]. End: 2-way wg merge in LDS
// (ML aliases pl, Of aliases vt), direct attnb write.
__global__ __launch_bounds__(512, 1) void k_attn(const u16* __restrict__ qb,
                                                 const u16* __restrict__ xb,
                                                 const float* __restrict__ bvec,
                                                 u16* __restrict__ attnb) {
  extern __shared__ u16 lds[];
  const int tid = threadIdx.x;
  const int w = tid >> 6, lane = tid & 63;
  const int wr = w & 3, wg = w >> 2;
  const int n = lane & 15, g = lane >> 4;
  const int b = blockIdx.x & 7, itile = blockIdx.x >> 3;
  const int i0 = itile * 64;
  const size_t xbase = (size_t)b * (NS * NF);

  char* vt = reinterpret_cast<char*>(lds) + w * 16384;   // private [256 f][32 j]
  char* pl = reinterpret_cast<char*>(lds) + 131072 + w * 1024;

  // Q fragments for this wave's 16 rows: 8 ks chunks
  u16x8 qf[8];
  {
    const u16* qrow = qb + xbase + (size_t)(i0 + 16 * wr + n) * NF + 8 * g;
    #pragma unroll
    for (int ks = 0; ks < 8; ++ks) qf[ks] = *reinterpret_cast<const u16x8*>(qrow + 32 * ks);
  }

  f32x4 O[16];
  #pragma unroll
  for (int nf = 0; nf < 16; ++nf) O[nf] = 0.f;
  float mrow[4], lpart[4];
  #pragma unroll
  for (int r = 0; r < 4; ++r) { mrow[r] = -__builtin_inff(); lpart[r] = 0.f; }

  for (int it = 0; it < 32; ++it) {
    const int j0 = (it * 2 + wg) * 32;
    // ---- stage private V^T [256 f][32 j], pair-packed b32 -----------------
    // lane roles: n = j-pair (0..15), g = f-chunk (0..3); 8 chunk-iters.
    #pragma unroll
    for (int itc = 0; itc < 8; ++itc) {
      const int c = 8 * (g + 4 * itc);
      const u16* r0 = xb + xbase + (size_t)(j0 + 2 * n) * NF + c;
      u16x8 v0 = *reinterpret_cast<const u16x8*>(r0);
      u16x8 v1 = *reinterpret_cast<const u16x8*>(r0 + NF);
      #pragma unroll
      for (int i = 0; i < 8; ++i) {
        const int f = c + i;
        const u32 pk = (u32)v0[i] | ((u32)v1[i] << 16);
        *reinterpret_cast<u32*>(vt + f * 64 + 4 * n) = pk;
      }
    }
    // ---- QK^T: 2 nf x 8 ks, K B-frags direct from global (L1/L2) ----------
    f32x4 sc[2];
    #pragma unroll
    for (int nf = 0; nf < 2; ++nf) {
      f32x4 acc = 0.f;
      const u16* krow = xb + xbase + (size_t)(j0 + 16 * nf + n) * NF + 8 * g;
      __builtin_amdgcn_s_setprio(1);
      #pragma unroll
      for (int ks = 0; ks < 8; ++ks) {
        u16x8 kf = *reinterpret_cast<const u16x8*>(krow + 32 * ks);
        acc = MFMA16(qf[ks], kf, acc);
      }
      __builtin_amdgcn_s_setprio(0);
      const float bv = bvec[b * NS + j0 + 16 * nf + n];
      #pragma unroll
      for (int r = 0; r < 4; ++r) sc[nf][r] = acc[r] + bv;
    }
    // ---- softmax: reduce-free fast path (T13 any-check) -------------------
    int needi = 0;
    #pragma unroll
    for (int nf = 0; nf < 2; ++nf)
      #pragma unroll
      for (int r = 0; r < 4; ++r) needi |= (sc[nf][r] > mrow[r] + 8.0f) ? 1 : 0;
    if (__any(needi)) {               // rare: true row-max reduce + rescale
      #pragma unroll
      for (int r = 0; r < 4; ++r) {
        float v = fmaxf(sc[0][r], sc[1][r]);
        #pragma unroll
        for (int m = 1; m < 16; m <<= 1) v = fmaxf(v, __shfl_xor(v, m, 64));
        const float mn = fmaxf(mrow[r], v);
        const float scl = __expf(mrow[r] - mn);
        mrow[r] = mn; lpart[r] *= scl;
        #pragma unroll
        for (int nf16 = 0; nf16 < 16; ++nf16) O[nf16][r] *= scl;
      }
    }
    float p[2][4];
    #pragma unroll
    for (int nf = 0; nf < 2; ++nf)
      #pragma unroll
      for (int r = 0; r < 4; ++r) p[nf][r] = __expf(sc[nf][r] - mrow[r]);
    #pragma unroll
    for (int r = 0; r < 4; ++r) lpart[r] += p[0][r] + p[1][r];  // per-lane partial
    // ---- P -> pl [16 row][32 j] swizzled -> pa ----------------------------
    #pragma unroll
    for (int nf = 0; nf < 2; ++nf)
      #pragma unroll
      for (int r = 0; r < 4; ++r) {
        const int row = 4 * g + r, colp = 16 * nf + n;
        const int byte = (row * 64 + 2 * colp) ^ ((row & 3) << 4);
        *reinterpret_cast<u16*>(pl + byte) = f2bf(p[nf][r]);
      }
    const int pbyte = (n * 64 + 16 * g) ^ ((n & 3) << 4);
    u16x8 pa = *reinterpret_cast<const u16x8*>(pl + pbyte);
    // ---- PV: 16 nf16, single K=32 step ------------------------------------
    __builtin_amdgcn_s_setprio(1);
    #pragma unroll
    for (int nf16 = 0; nf16 < 16; ++nf16) {
      const int f = 16 * nf16 + n;
      u16x8 vf = *reinterpret_cast<const u16x8*>(vt + f * 64 + 16 * g);
      O[nf16] = MFMA16(pa, vf, O[nf16]);
    }
    __builtin_amdgcn_s_setprio(0);
  }

  // ---- one-time row-sum reduce across n-lanes -----------------------------
  float lrow[4];
  #pragma unroll
  for (int r = 0; r < 4; ++r) {
    float s = lpart[r];
    #pragma unroll
    for (int m = 1; m < 16; m <<= 1) s += __shfl_xor(s, m, 64);
    lrow[r] = s;
  }
  __syncthreads();                                   // loop LDS dead
  // ---- 2-way merge across wg; direct attnb write --------------------------
  float* MLm = reinterpret_cast<float*>(reinterpret_cast<char*>(lds) + 131072);
  if (n == 0) {
    #pragma unroll
    for (int r = 0; r < 4; ++r) {
      const int row = 16 * wr + 4 * g + r;
      MLm[(wg * 64 + row) * 2]     = mrow[r];
      MLm[(wg * 64 + row) * 2 + 1] = lrow[r];
    }
  }
  __syncthreads();                                   // B1
  float fac[4], rL[4];
  #pragma unroll
  for (int r = 0; r < 4; ++r) {
    const int row = 16 * wr + 4 * g + r;
    const float m0 = MLm[row * 2],        l0 = MLm[row * 2 + 1];
    const float m1 = MLm[(64 + row) * 2], l1 = MLm[(64 + row) * 2 + 1];
    const float M = fmaxf(m0, m1);
    const float L = l0 * __expf(m0 - M) + l1 * __expf(m1 - M);
    fac[r] = __expf(mrow[r] - M);
    rL[r]  = 1.0f / L;
  }
  char* Of = reinterpret_cast<char*>(lds);           // aliases vt (dead)
  #define OBYTE(row, col) (((row) * 1024 + 4 * (col)) ^ (((row) & 12) << 3))
  if (wg == 1) {
    #pragma unroll
    for (int nf16 = 0; nf16 < 16; ++nf16)
      #pragma unroll
      for (int r = 0; r < 4; ++r) {
        const int row = 16 * wr + 4 * g + r, col = 16 * nf16 + n;
        *reinterpret_cast<float*>(Of + OBYTE(row, col)) = O[nf16][r] * fac[r];
      }
  }
  __syncthreads();                                   // B2
  if (wg == 0) {
    #pragma unroll
    for (int nf16 = 0; nf16 < 16; ++nf16)
      #pragma unroll
      for (int r = 0; r < 4; ++r) {
        const int row = 16 * wr + 4 * g + r, col = 16 * nf16 + n;
        const float v = (O[nf16][r] * fac[r] +
            *reinterpret_cast<const float*>(Of + OBYTE(row, col))) * rL[r];
        attnb[xbase + (size_t)(i0 + row) * NF + col] = f2bf(v);
      }
  }
}

// ---------------- fused gate GEMMs + epilogue ------------------------------
// grid 1024 x 256 thr: block = 16 rows; wave w -> col quarter (nt = 4w+nt2).
__global__ __launch_bounds__(256, 4) void k_gate(const u16* __restrict__ xb,
                                                 const u16* __restrict__ attnb,
                                                 const float* __restrict__ x,
                                                 const float* __restrict__ zb,
                                                 const float* __restrict__ rb,
                                                 const float* __restrict__ fb,
                                                 const u16* __restrict__ wfrag,
                                                 float* __restrict__ out) {
  const int tid = threadIdx.x, w = tid >> 6, lane = tid & 63;
  const int m0 = blockIdx.x * 16;
  const int n = lane & 15, g = lane >> 4;

  u16x8 af[16];
  {
    const int row = m0 + n;
    const u16* xr = xb + (size_t)row * NF + 8 * g;
    #pragma unroll
    for (int ks = 0; ks < 8; ++ks) af[ks] = *reinterpret_cast<const u16x8*>(xr + 32 * ks);
    const u16* ar = attnb + (size_t)row * NF + 8 * g;
    #pragma unroll
    for (int ks = 0; ks < 8; ++ks) af[8 + ks] = *reinterpret_cast<const u16x8*>(ar + 32 * ks);
  }
  #pragma unroll
  for (int nt2 = 0; nt2 < 4; ++nt2) {
    const int nt = 4 * w + nt2;
    const int col = 16 * nt + n;
    f32x4 za = zb[col], ra = rb[col], fa = fb[col];
    #pragma unroll
    for (int ks = 0; ks < 16; ++ks) {
      const size_t base = ((size_t)(ks * 16 + nt) * 64 + lane) * 8;
      u16x8 bz  = *reinterpret_cast<const u16x8*>(wfrag + base);
      u16x8 br  = *reinterpret_cast<const u16x8*>(wfrag + (size_t)256 * 64 * 8 + base);
      u16x8 bff = *reinterpret_cast<const u16x8*>(wfrag + (size_t)512 * 64 * 8 + base);
      za = MFMA16(af[ks], bz, za);
      ra = MFMA16(af[ks], br, ra);
      fa = MFMA16(af[ks], bff, fa);
    }
    #pragma unroll
    for (int r = 0; r < 4; ++r) {
      const int row = m0 + 4 * g + r;
      const float xv = x[(size_t)row * NF + col];
      const float zv = 2.f / (1.f + __expf(-2.f * za[r])) - 1.f;  // tanh
      const float rv = 1.f / (1.f + __expf(-ra[r]));
      const float fv = 1.f / (1.f + __expf(-fa[r]));
      out[(size_t)row * NF + col] = rv * xv + fv * zv;
    }
  }
}

// ---------------------------------------------------------------------------
extern "C" void kernel_launch(void* const* d_in, const int* in_sizes, int n_in,
                              void* d_out, int out_size, void* d_ws, size_t ws_size,
                              hipStream_t stream) {
  const float* x    = (const float*)d_in[0];
  const float* attw = (const float*)d_in[1];
  const float* zw   = (const float*)d_in[2];
  const float* zb   = (const float*)d_in[3];
  const float* rw   = (const float*)d_in[4];
  const float* rb   = (const float*)d_in[5];
  const float* fw   = (const float*)d_in[6];
  const float* fb   = (const float*)d_in[7];
  float* out = (float*)d_out;

  char* ws = (char*)d_ws;
  u16*   qb    = (u16*)(ws);                       //  8 MB
  u16*   xbb   = (u16*)(ws + 8388608);             //  8 MB
  u16*   attnb = (u16*)(ws + 16777216);            //  8 MB
  float* bvec  = (float*)(ws + 25165824);          // 64 KB
  u16*   wfrag = (u16*)(ws + 25231360);            // 768 KB

  (void)hipFuncSetAttribute((const void*)k_attn,
      hipFuncAttributeMaxDynamicSharedMemorySize, 139264);

  k_prep<<<NR / 4, 256, 0, stream>>>(x, attw, qb, xbb, bvec);
  k_wrep<<<768, 64, 0, stream>>>(zw, rw, fw, wfrag);
  k_attn<<<256, 512, 139264, stream>>>(qb, xbb, bvec, attnb);
  k_gate<<<1024, 256, 0, stream>>>(xbb, attnb, x, zb, rb, fb, wfrag, out);
}